// Round 5
// baseline (836.829 us; speedup 1.0000x reference)
//
#include <hip/hip_runtime.h>
#include <hip/hip_bf16.h>

// sigmoid(x) = 1 / (1 + e^-x); __expf -> v_mul + v_exp_f32, rcpf -> v_rcp_f32.
__device__ __forceinline__ float sigmoidf_fast(float v) {
    return __builtin_amdgcn_rcpf(1.0f + __expf(-v));
}

// ---------------- Pass A: gather + MLP -> linear weight store ----------------
__global__ __launch_bounds__(256) void mesh_mlp_kernel(
    const float* __restrict__ points,
    const int*   __restrict__ adj,
    const float* __restrict__ W1, const float* __restrict__ b1,
    const float* __restrict__ W2, const float* __restrict__ b2,
    const float* __restrict__ W3, const float* __restrict__ b3,
    const float* __restrict__ W4, const float* __restrict__ b4,
    float* __restrict__ elw,      // [3 * n_elems] element weights, linear
    int n_elems)
{
    const int e = blockIdx.x * 256 + threadIdx.x;
    if (e >= n_elems) return;

    const int i0 = adj[3 * e + 0];
    const int i1 = adj[3 * e + 1];
    const int i2 = adj[3 * e + 2];
    const float2* pts2 = (const float2*)points;
    const float2 p0 = pts2[i0];
    const float2 p1 = pts2[i1];
    const float2 p2 = pts2[i2];

    const float x[6] = { p0.x, p0.y, p1.x, p1.y, p2.x, p2.y };

    // Weight loads are wave-uniform -> scalar s_load into SGPRs (free).
    float h[8], g[8];
    #pragma unroll
    for (int j = 0; j < 8; ++j) h[j] = b1[j];
    #pragma unroll
    for (int i = 0; i < 6; ++i) {
        const float xi = x[i];
        #pragma unroll
        for (int j = 0; j < 8; ++j) h[j] = fmaf(xi, W1[i * 8 + j], h[j]);
    }
    #pragma unroll
    for (int j = 0; j < 8; ++j) h[j] = sigmoidf_fast(h[j]);

    #pragma unroll
    for (int j = 0; j < 8; ++j) g[j] = b2[j];
    #pragma unroll
    for (int i = 0; i < 8; ++i) {
        const float hi = h[i];
        #pragma unroll
        for (int j = 0; j < 8; ++j) g[j] = fmaf(hi, W2[i * 8 + j], g[j]);
    }
    #pragma unroll
    for (int j = 0; j < 8; ++j) g[j] = sigmoidf_fast(g[j]);

    #pragma unroll
    for (int j = 0; j < 8; ++j) h[j] = b3[j];
    #pragma unroll
    for (int i = 0; i < 8; ++i) {
        const float gi = g[i];
        #pragma unroll
        for (int j = 0; j < 8; ++j) h[j] = fmaf(gi, W3[i * 8 + j], h[j]);
    }
    #pragma unroll
    for (int j = 0; j < 8; ++j) h[j] = sigmoidf_fast(h[j]);

    float o0 = b4[0], o1 = b4[1], o2 = b4[2];
    #pragma unroll
    for (int i = 0; i < 8; ++i) {
        const float hi = h[i];
        o0 = fmaf(hi, W4[i * 3 + 0], o0);
        o1 = fmaf(hi, W4[i * 3 + 1], o1);
        o2 = fmaf(hi, W4[i * 3 + 2], o2);
    }
    // coalesced 12 B/thread linear store
    elw[3 * e + 0] = sigmoidf_fast(o0);
    elw[3 * e + 1] = sigmoidf_fast(o1);
    elw[3 * e + 2] = sigmoidf_fast(o2);
}

// ---------------- Pass B: linear load -> scatter-add ----------------
// One thread per 4 (index, weight) pairs; adjacency IS the index array in
// pair order, so no index copy is needed.
__global__ __launch_bounds__(256) void mesh_scatter_kernel(
    const int*   __restrict__ adj,
    const float* __restrict__ elw,
    float* __restrict__ out,
    int n_pairs)
{
    const int j = (blockIdx.x * 256 + threadIdx.x) * 4;
    if (j + 3 < n_pairs) {
        const int4   idx = *(const int4*)(adj + j);
        const float4 w   = *(const float4*)(elw + j);
        unsafeAtomicAdd(&out[idx.x], w.x);
        unsafeAtomicAdd(&out[idx.y], w.y);
        unsafeAtomicAdd(&out[idx.z], w.z);
        unsafeAtomicAdd(&out[idx.w], w.w);
    } else {
        for (int k = j; k < n_pairs; ++k)
            unsafeAtomicAdd(&out[adj[k]], elw[k]);
    }
}

// ---------------- Fallback: fused single pass (known-good) ----------------
__global__ __launch_bounds__(256) void mesh_fused_kernel(
    const float* __restrict__ points,
    const int*   __restrict__ adj,
    const float* __restrict__ W1, const float* __restrict__ b1,
    const float* __restrict__ W2, const float* __restrict__ b2,
    const float* __restrict__ W3, const float* __restrict__ b3,
    const float* __restrict__ W4, const float* __restrict__ b4,
    float* __restrict__ out,
    int n_elems)
{
    const int e = blockIdx.x * 256 + threadIdx.x;
    if (e >= n_elems) return;
    const int i0 = adj[3 * e + 0], i1 = adj[3 * e + 1], i2 = adj[3 * e + 2];
    const float2* pts2 = (const float2*)points;
    const float2 p0 = pts2[i0], p1 = pts2[i1], p2 = pts2[i2];
    const float x[6] = { p0.x, p0.y, p1.x, p1.y, p2.x, p2.y };
    float h[8], g[8];
    #pragma unroll
    for (int j = 0; j < 8; ++j) h[j] = b1[j];
    #pragma unroll
    for (int i = 0; i < 6; ++i) {
        const float xi = x[i];
        #pragma unroll
        for (int j = 0; j < 8; ++j) h[j] = fmaf(xi, W1[i * 8 + j], h[j]);
    }
    #pragma unroll
    for (int j = 0; j < 8; ++j) h[j] = sigmoidf_fast(h[j]);
    #pragma unroll
    for (int j = 0; j < 8; ++j) g[j] = b2[j];
    #pragma unroll
    for (int i = 0; i < 8; ++i) {
        const float hi = h[i];
        #pragma unroll
        for (int j = 0; j < 8; ++j) g[j] = fmaf(hi, W2[i * 8 + j], g[j]);
    }
    #pragma unroll
    for (int j = 0; j < 8; ++j) g[j] = sigmoidf_fast(g[j]);
    #pragma unroll
    for (int j = 0; j < 8; ++j) h[j] = b3[j];
    #pragma unroll
    for (int i = 0; i < 8; ++i) {
        const float gi = g[i];
        #pragma unroll
        for (int j = 0; j < 8; ++j) h[j] = fmaf(gi, W3[i * 8 + j], h[j]);
    }
    #pragma unroll
    for (int j = 0; j < 8; ++j) h[j] = sigmoidf_fast(h[j]);
    float o0 = b4[0], o1 = b4[1], o2 = b4[2];
    #pragma unroll
    for (int i = 0; i < 8; ++i) {
        const float hi = h[i];
        o0 = fmaf(hi, W4[i * 3 + 0], o0);
        o1 = fmaf(hi, W4[i * 3 + 1], o1);
        o2 = fmaf(hi, W4[i * 3 + 2], o2);
    }
    unsafeAtomicAdd(&out[i0], sigmoidf_fast(o0));
    unsafeAtomicAdd(&out[i1], sigmoidf_fast(o1));
    unsafeAtomicAdd(&out[i2], sigmoidf_fast(o2));
}

extern "C" void kernel_launch(void* const* d_in, const int* in_sizes, int n_in,
                              void* d_out, int out_size, void* d_ws, size_t ws_size,
                              hipStream_t stream) {
    const float* points = (const float*)d_in[0];
    const int*   adj    = (const int*)d_in[1];
    const float* W1 = (const float*)d_in[2];
    const float* b1 = (const float*)d_in[3];
    const float* W2 = (const float*)d_in[4];
    const float* b2 = (const float*)d_in[5];
    const float* W3 = (const float*)d_in[6];
    const float* b3 = (const float*)d_in[7];
    const float* W4 = (const float*)d_in[8];
    const float* b4 = (const float*)d_in[9];
    float* out = (float*)d_out;

    const int n_elems  = in_sizes[1] / 3;  // adjacency is [E,3]
    const int n_pairs  = in_sizes[1];
    const int block = 256;

    const size_t need = (size_t)n_pairs * sizeof(float);  // elw scratch (48 MB)
    if (ws_size >= need) {
        float* elw = (float*)d_ws;
        hipMemsetAsync(out, 0, (size_t)out_size * sizeof(float), stream);
        const int grid1 = (n_elems + block - 1) / block;
        mesh_mlp_kernel<<<grid1, block, 0, stream>>>(
            points, adj, W1, b1, W2, b2, W3, b3, W4, b4, elw, n_elems);
        const int grid2 = (n_pairs / 4 + block - 1) / block;
        mesh_scatter_kernel<<<grid2, block, 0, stream>>>(adj, elw, out, n_pairs);
    } else {
        hipMemsetAsync(out, 0, (size_t)out_size * sizeof(float), stream);
        const int grid1 = (n_elems + block - 1) / block;
        mesh_fused_kernel<<<grid1, block, 0, stream>>>(
            points, adj, W1, b1, W2, b2, W3, b3, W4, b4, out, n_elems);
    }
}

// Round 6
// 460.064 us; speedup vs baseline: 1.8189x; 1.8189x over previous
//
#include <hip/hip_runtime.h>
#include <hip/hip_bf16.h>

// ---- binning geometry ----
#define WIN_SHIFT   13                 // vertex window = 8192 vertices
#define WIN_SIZE    (1 << WIN_SHIFT)
#define K_BUCKETS   245                // ceil(2,000,000 / 8192)
#define BUCKET_CAP  51200              // mean 49152 + ~9 sigma
#define CHUNK_E     2048               // elements per phase-A block
#define CHUNK_P     (3 * CHUNK_E)      // 6144 pairs per phase-A block

// sigmoid(x) = 1 / (1 + e^-x); __expf -> v_mul + v_exp_f32, rcpf -> v_rcp_f32.
__device__ __forceinline__ float sigmoidf_fast(float v) {
    return __builtin_amdgcn_rcpf(1.0f + __expf(-v));
}

// Tiny MLP 6->8->8->8->3, sigmoid after each layer. Weight loads are
// wave-uniform (kernel-arg pointers + compile-time indices) -> scalar s_load.
__device__ __forceinline__ void mlp3(
    const float x[6],
    const float* __restrict__ W1, const float* __restrict__ b1,
    const float* __restrict__ W2, const float* __restrict__ b2,
    const float* __restrict__ W3, const float* __restrict__ b3,
    const float* __restrict__ W4, const float* __restrict__ b4,
    float& o0, float& o1, float& o2)
{
    float h[8], g[8];
    #pragma unroll
    for (int j = 0; j < 8; ++j) h[j] = b1[j];
    #pragma unroll
    for (int i = 0; i < 6; ++i) {
        const float xi = x[i];
        #pragma unroll
        for (int j = 0; j < 8; ++j) h[j] = fmaf(xi, W1[i * 8 + j], h[j]);
    }
    #pragma unroll
    for (int j = 0; j < 8; ++j) h[j] = sigmoidf_fast(h[j]);
    #pragma unroll
    for (int j = 0; j < 8; ++j) g[j] = b2[j];
    #pragma unroll
    for (int i = 0; i < 8; ++i) {
        const float hi = h[i];
        #pragma unroll
        for (int j = 0; j < 8; ++j) g[j] = fmaf(hi, W2[i * 8 + j], g[j]);
    }
    #pragma unroll
    for (int j = 0; j < 8; ++j) g[j] = sigmoidf_fast(g[j]);
    #pragma unroll
    for (int j = 0; j < 8; ++j) h[j] = b3[j];
    #pragma unroll
    for (int i = 0; i < 8; ++i) {
        const float gi = g[i];
        #pragma unroll
        for (int j = 0; j < 8; ++j) h[j] = fmaf(gi, W3[i * 8 + j], h[j]);
    }
    #pragma unroll
    for (int j = 0; j < 8; ++j) h[j] = sigmoidf_fast(h[j]);
    float a0 = b4[0], a1 = b4[1], a2 = b4[2];
    #pragma unroll
    for (int i = 0; i < 8; ++i) {
        const float hi = h[i];
        a0 = fmaf(hi, W4[i * 3 + 0], a0);
        a1 = fmaf(hi, W4[i * 3 + 1], a1);
        a2 = fmaf(hi, W4[i * 3 + 2], a2);
    }
    o0 = sigmoidf_fast(a0);
    o1 = sigmoidf_fast(a1);
    o2 = sigmoidf_fast(a2);
}

// ---------------- Phase A: histogram -> reserve -> MLP + bin-scatter ----------------
__global__ __launch_bounds__(256) void mesh_bin_kernel(
    const float* __restrict__ points,
    const int*   __restrict__ adj,
    const float* __restrict__ W1, const float* __restrict__ b1,
    const float* __restrict__ W2, const float* __restrict__ b2,
    const float* __restrict__ W3, const float* __restrict__ b3,
    const float* __restrict__ W4, const float* __restrict__ b4,
    uint2*    __restrict__ buckets,   // [K_BUCKETS][BUCKET_CAP]
    unsigned* __restrict__ gcount,    // [256] global bucket counters (pre-zeroed)
    float*    __restrict__ out,       // overflow fallback target (pre-zeroed)
    int n_elems, int n_pairs)
{
    __shared__ unsigned hist[256];    // K_BUCKETS <= 256
    __shared__ unsigned gbase[256];
    __shared__ unsigned cursor[256];
    const int t = threadIdx.x;
    hist[t] = 0u;
    cursor[t] = 0u;
    __syncthreads();

    // 1) histogram of this chunk's 6144 vertex ids (coalesced adj reads)
    const int pbase = blockIdx.x * CHUNK_P;
    #pragma unroll
    for (int i = 0; i < CHUNK_P / 256; ++i) {
        const int j = pbase + t + i * 256;
        if (j < n_pairs) atomicAdd(&hist[((unsigned)adj[j]) >> WIN_SHIFT], 1u);
    }
    __syncthreads();

    // 2) reserve contiguous global space per bucket (one atomic per nonzero bucket)
    {
        const unsigned c = hist[t];
        gbase[t] = c ? atomicAdd(&gcount[t], c) : 0u;
    }
    __syncthreads();

    // 3) gather + MLP + binned scatter
    const int ebase = blockIdx.x * CHUNK_E;
    const float2* pts2 = (const float2*)points;
    for (int i = 0; i < CHUNK_E / 256; ++i) {
        const int e = ebase + t + i * 256;
        if (e < n_elems) {
            const int i0 = adj[3 * e + 0];
            const int i1 = adj[3 * e + 1];
            const int i2 = adj[3 * e + 2];
            const float2 p0 = pts2[i0];
            const float2 p1 = pts2[i1];
            const float2 p2 = pts2[i2];
            const float x[6] = { p0.x, p0.y, p1.x, p1.y, p2.x, p2.y };
            float o0, o1, o2;
            mlp3(x, W1, b1, W2, b2, W3, b3, W4, b4, o0, o1, o2);

            const int   vv[3] = { i0, i1, i2 };
            const float ww[3] = { o0, o1, o2 };
            #pragma unroll
            for (int k = 0; k < 3; ++k) {
                const unsigned v = (unsigned)vv[k];
                const unsigned b = v >> WIN_SHIFT;
                const unsigned loc  = atomicAdd(&cursor[b], 1u);  // ds_add_rtn
                const unsigned slot = gbase[b] + loc;
                if (slot < BUCKET_CAP)
                    buckets[(size_t)b * BUCKET_CAP + slot] =
                        make_uint2(v, __float_as_uint(ww[k]));
                else
                    unsafeAtomicAdd(&out[v], ww[k]);  // ~never taken; correctness net
            }
        }
    }
}

// ---------------- Phase B: per-window LDS reduce -> coalesced out ----------------
__global__ __launch_bounds__(256) void mesh_reduce_kernel(
    const uint2*    __restrict__ buckets,
    const unsigned* __restrict__ gcount,
    float* __restrict__ out, int n_points)
{
    __shared__ float acc[WIN_SIZE];   // 32 KB
    const int t = threadIdx.x;
    const int b = blockIdx.x;
    #pragma unroll
    for (int i = 0; i < WIN_SIZE / 256; ++i) acc[t + i * 256] = 0.f;
    __syncthreads();

    const unsigned n = min(gcount[b], (unsigned)BUCKET_CAP);
    const size_t base = (size_t)b * BUCKET_CAP;
    for (unsigned i = t; i < n; i += 256) {
        const uint2 e = buckets[base + i];
        atomicAdd(&acc[e.x & (WIN_SIZE - 1)], __uint_as_float(e.y));  // LDS atomic
    }
    __syncthreads();

    const int vb = b << WIN_SHIFT;
    #pragma unroll
    for (int i = 0; i < WIN_SIZE / 256; ++i) {
        const int v = vb + t + i * 256;
        if (v < n_points) out[v] += acc[t + i * 256];  // += keeps overflow atomics
    }
}

// ---------------- Fallback: fused single pass (known-good, 588 us) ----------------
__global__ __launch_bounds__(256) void mesh_fused_kernel(
    const float* __restrict__ points,
    const int*   __restrict__ adj,
    const float* __restrict__ W1, const float* __restrict__ b1,
    const float* __restrict__ W2, const float* __restrict__ b2,
    const float* __restrict__ W3, const float* __restrict__ b3,
    const float* __restrict__ W4, const float* __restrict__ b4,
    float* __restrict__ out,
    int n_elems)
{
    const int e = blockIdx.x * 256 + threadIdx.x;
    if (e >= n_elems) return;
    const int i0 = adj[3 * e + 0], i1 = adj[3 * e + 1], i2 = adj[3 * e + 2];
    const float2* pts2 = (const float2*)points;
    const float2 p0 = pts2[i0], p1 = pts2[i1], p2 = pts2[i2];
    const float x[6] = { p0.x, p0.y, p1.x, p1.y, p2.x, p2.y };
    float o0, o1, o2;
    mlp3(x, W1, b1, W2, b2, W3, b3, W4, b4, o0, o1, o2);
    unsafeAtomicAdd(&out[i0], o0);
    unsafeAtomicAdd(&out[i1], o1);
    unsafeAtomicAdd(&out[i2], o2);
}

extern "C" void kernel_launch(void* const* d_in, const int* in_sizes, int n_in,
                              void* d_out, int out_size, void* d_ws, size_t ws_size,
                              hipStream_t stream) {
    const float* points = (const float*)d_in[0];
    const int*   adj    = (const int*)d_in[1];
    const float* W1 = (const float*)d_in[2];
    const float* b1 = (const float*)d_in[3];
    const float* W2 = (const float*)d_in[4];
    const float* b2 = (const float*)d_in[5];
    const float* W3 = (const float*)d_in[6];
    const float* b3 = (const float*)d_in[7];
    const float* W4 = (const float*)d_in[8];
    const float* b4 = (const float*)d_in[9];
    float* out = (float*)d_out;

    const int n_elems  = in_sizes[1] / 3;  // adjacency is [E,3]
    const int n_pairs  = in_sizes[1];
    const int n_points = out_size;
    const int block = 256;

    // ws layout: [gcount: 256 u32][buckets: K_BUCKETS * BUCKET_CAP uint2]
    const size_t need = 1024 + (size_t)K_BUCKETS * BUCKET_CAP * sizeof(uint2);

    if (ws_size >= need && n_points <= K_BUCKETS * WIN_SIZE) {
        unsigned* gcount = (unsigned*)d_ws;
        uint2* buckets = (uint2*)((char*)d_ws + 1024);

        hipMemsetAsync(gcount, 0, 1024, stream);
        hipMemsetAsync(out, 0, (size_t)n_points * sizeof(float), stream);

        const int gridA = (n_elems + CHUNK_E - 1) / CHUNK_E;
        mesh_bin_kernel<<<gridA, block, 0, stream>>>(
            points, adj, W1, b1, W2, b2, W3, b3, W4, b4,
            buckets, gcount, out, n_elems, n_pairs);

        mesh_reduce_kernel<<<K_BUCKETS, block, 0, stream>>>(
            buckets, gcount, out, n_points);
    } else {
        hipMemsetAsync(out, 0, (size_t)n_points * sizeof(float), stream);
        const int grid1 = (n_elems + block - 1) / block;
        mesh_fused_kernel<<<grid1, block, 0, stream>>>(
            points, adj, W1, b1, W2, b2, W3, b3, W4, b4, out, n_elems);
    }
}

// Round 7
// 456.226 us; speedup vs baseline: 1.8342x; 1.0084x over previous
//
#include <hip/hip_runtime.h>
#include <hip/hip_bf16.h>

// ---- binning geometry ----
#define WIN_SHIFT   13                 // vertex window = 8192 vertices
#define WIN_SIZE    (1 << WIN_SHIFT)
#define K_BUCKETS   245                // ceil(2,000,000 / 8192)
#define BUCKET_CAP  51200              // mean 49152 + ~9 sigma
#define CHUNK_E     2048               // elements per phase-A block
#define CHUNK_P     (3 * CHUNK_E)      // 6144 pairs per phase-A block

// sigmoid(x) = 1 / (1 + e^-x); __expf -> v_mul + v_exp_f32, rcpf -> v_rcp_f32.
__device__ __forceinline__ float sigmoidf_fast(float v) {
    return __builtin_amdgcn_rcpf(1.0f + __expf(-v));
}

// Tiny MLP 6->8->8->8->3, sigmoid after each layer. Weight loads are
// wave-uniform (kernel-arg pointers + compile-time indices) -> scalar s_load.
__device__ __forceinline__ void mlp3(
    const float x[6],
    const float* __restrict__ W1, const float* __restrict__ b1,
    const float* __restrict__ W2, const float* __restrict__ b2,
    const float* __restrict__ W3, const float* __restrict__ b3,
    const float* __restrict__ W4, const float* __restrict__ b4,
    float& o0, float& o1, float& o2)
{
    float h[8], g[8];
    #pragma unroll
    for (int j = 0; j < 8; ++j) h[j] = b1[j];
    #pragma unroll
    for (int i = 0; i < 6; ++i) {
        const float xi = x[i];
        #pragma unroll
        for (int j = 0; j < 8; ++j) h[j] = fmaf(xi, W1[i * 8 + j], h[j]);
    }
    #pragma unroll
    for (int j = 0; j < 8; ++j) h[j] = sigmoidf_fast(h[j]);
    #pragma unroll
    for (int j = 0; j < 8; ++j) g[j] = b2[j];
    #pragma unroll
    for (int i = 0; i < 8; ++i) {
        const float hi = h[i];
        #pragma unroll
        for (int j = 0; j < 8; ++j) g[j] = fmaf(hi, W2[i * 8 + j], g[j]);
    }
    #pragma unroll
    for (int j = 0; j < 8; ++j) g[j] = sigmoidf_fast(g[j]);
    #pragma unroll
    for (int j = 0; j < 8; ++j) h[j] = b3[j];
    #pragma unroll
    for (int i = 0; i < 8; ++i) {
        const float gi = g[i];
        #pragma unroll
        for (int j = 0; j < 8; ++j) h[j] = fmaf(gi, W3[i * 8 + j], h[j]);
    }
    #pragma unroll
    for (int j = 0; j < 8; ++j) h[j] = sigmoidf_fast(h[j]);
    float a0 = b4[0], a1 = b4[1], a2 = b4[2];
    #pragma unroll
    for (int i = 0; i < 8; ++i) {
        const float hi = h[i];
        a0 = fmaf(hi, W4[i * 3 + 0], a0);
        a1 = fmaf(hi, W4[i * 3 + 1], a1);
        a2 = fmaf(hi, W4[i * 3 + 2], a2);
    }
    o0 = sigmoidf_fast(a0);
    o1 = sigmoidf_fast(a1);
    o2 = sigmoidf_fast(a2);
}

__device__ __forceinline__ void scatter3(
    uint2* __restrict__ buckets, unsigned* cursor, const unsigned* gbase,
    float* __restrict__ out,
    int v0, int v1, int v2, float w0, float w1, float w2)
{
    const int   vv[3] = { v0, v1, v2 };
    const float ww[3] = { w0, w1, w2 };
    #pragma unroll
    for (int k = 0; k < 3; ++k) {
        const unsigned v = (unsigned)vv[k];
        const unsigned b = v >> WIN_SHIFT;
        const unsigned loc  = atomicAdd(&cursor[b], 1u);   // ds_add_rtn
        const unsigned slot = gbase[b] + loc;
        if (slot < BUCKET_CAP)
            buckets[(size_t)b * BUCKET_CAP + slot] = make_uint2(v, __float_as_uint(ww[k]));
        else
            unsafeAtomicAdd(&out[v], ww[k]);               // ~never taken; correctness net
    }
}

// ---------------- Phase A: histogram -> reserve -> MLP + bin-scatter ----------------
__global__ __launch_bounds__(256) void mesh_bin_kernel(
    const float* __restrict__ points,
    const int*   __restrict__ adj,
    const float* __restrict__ W1, const float* __restrict__ b1,
    const float* __restrict__ W2, const float* __restrict__ b2,
    const float* __restrict__ W3, const float* __restrict__ b3,
    const float* __restrict__ W4, const float* __restrict__ b4,
    uint2*    __restrict__ buckets,   // [K_BUCKETS][BUCKET_CAP]
    unsigned* __restrict__ gcount,    // [256] global bucket counters (pre-zeroed)
    float*    __restrict__ out,       // overflow fallback target (pre-zeroed)
    int n_elems, int n_pairs)
{
    __shared__ unsigned hist[256];    // K_BUCKETS <= 256
    __shared__ unsigned gbase[256];
    __shared__ unsigned cursor[256];
    const int t = threadIdx.x;
    hist[t] = 0u;
    cursor[t] = 0u;
    __syncthreads();

    const bool full = (blockIdx.x + 1) * CHUNK_E <= n_elems;
    const int pbase = blockIdx.x * CHUNK_P;

    // 1) histogram of this chunk's 6144 vertex ids (coalesced adj reads)
    if (full) {
        #pragma unroll
        for (int i = 0; i < CHUNK_P / 256; ++i)
            atomicAdd(&hist[((unsigned)adj[pbase + t + i * 256]) >> WIN_SHIFT], 1u);
    } else {
        for (int i = 0; i < CHUNK_P / 256; ++i) {
            const int j = pbase + t + i * 256;
            if (j < n_pairs) atomicAdd(&hist[((unsigned)adj[j]) >> WIN_SHIFT], 1u);
        }
    }
    __syncthreads();

    // 2) reserve contiguous global space per bucket (one atomic per nonzero bucket)
    {
        const unsigned c = hist[t];
        gbase[t] = c ? atomicAdd(&gcount[t], c) : 0u;
    }
    __syncthreads();

    // 3) gather + MLP + binned scatter, unrolled x2: issue BOTH elements'
    // 12 loads before either MLP -> 2x memory-level parallelism; the two
    // independent MLPs interleave, hiding the exp/rcp latency chains.
    const int ebase = blockIdx.x * CHUNK_E;
    const float2* pts2 = (const float2*)points;

    if (full) {
        #pragma unroll
        for (int i = 0; i < CHUNK_E / 256; i += 2) {
            const int e0 = ebase + t + i * 256;
            const int e1 = e0 + 256;
            const int iA0 = adj[3 * e0 + 0];
            const int iA1 = adj[3 * e0 + 1];
            const int iA2 = adj[3 * e0 + 2];
            const int iB0 = adj[3 * e1 + 0];
            const int iB1 = adj[3 * e1 + 1];
            const int iB2 = adj[3 * e1 + 2];
            const float2 pA0 = pts2[iA0];
            const float2 pA1 = pts2[iA1];
            const float2 pA2 = pts2[iA2];
            const float2 pB0 = pts2[iB0];
            const float2 pB1 = pts2[iB1];
            const float2 pB2 = pts2[iB2];
            const float xA[6] = { pA0.x, pA0.y, pA1.x, pA1.y, pA2.x, pA2.y };
            const float xB[6] = { pB0.x, pB0.y, pB1.x, pB1.y, pB2.x, pB2.y };
            float oA0, oA1, oA2, oB0, oB1, oB2;
            mlp3(xA, W1, b1, W2, b2, W3, b3, W4, b4, oA0, oA1, oA2);
            mlp3(xB, W1, b1, W2, b2, W3, b3, W4, b4, oB0, oB1, oB2);
            scatter3(buckets, cursor, gbase, out, iA0, iA1, iA2, oA0, oA1, oA2);
            scatter3(buckets, cursor, gbase, out, iB0, iB1, iB2, oB0, oB1, oB2);
        }
    } else {
        for (int i = 0; i < CHUNK_E / 256; ++i) {
            const int e = ebase + t + i * 256;
            if (e < n_elems) {
                const int i0 = adj[3 * e + 0];
                const int i1 = adj[3 * e + 1];
                const int i2 = adj[3 * e + 2];
                const float2 p0 = pts2[i0];
                const float2 p1 = pts2[i1];
                const float2 p2 = pts2[i2];
                const float x[6] = { p0.x, p0.y, p1.x, p1.y, p2.x, p2.y };
                float o0, o1, o2;
                mlp3(x, W1, b1, W2, b2, W3, b3, W4, b4, o0, o1, o2);
                scatter3(buckets, cursor, gbase, out, i0, i1, i2, o0, o1, o2);
            }
        }
    }
}

// ---------------- Phase B: per-window LDS reduce -> coalesced out ----------------
// 1024 threads (16 waves/CU) + 4 entries/thread/iter via two uint4 loads:
// round 6 ran this with 4 waves/CU and one 8B load per iter -> latency-bound.
__global__ __launch_bounds__(1024) void mesh_reduce_kernel(
    const uint2*    __restrict__ buckets,
    const unsigned* __restrict__ gcount,
    float* __restrict__ out, int n_points)
{
    __shared__ float acc[WIN_SIZE];   // 32 KB
    const int t = threadIdx.x;
    const int b = blockIdx.x;
    #pragma unroll
    for (int i = 0; i < WIN_SIZE / 1024; ++i) acc[t + i * 1024] = 0.f;
    __syncthreads();

    const unsigned n = min(gcount[b], (unsigned)BUCKET_CAP);
    const size_t base = (size_t)b * BUCKET_CAP;

    // main: disjoint quads of 4 entries per thread (32 B/lane, coalesced)
    for (unsigned i = t * 4u; i + 4u <= n; i += 1024u * 4u) {
        const uint4 q0 = *(const uint4*)(buckets + base + i);       // entries i, i+1
        const uint4 q1 = *(const uint4*)(buckets + base + i + 2);   // entries i+2, i+3
        atomicAdd(&acc[q0.x & (WIN_SIZE - 1)], __uint_as_float(q0.y));
        atomicAdd(&acc[q0.z & (WIN_SIZE - 1)], __uint_as_float(q0.w));
        atomicAdd(&acc[q1.x & (WIN_SIZE - 1)], __uint_as_float(q1.y));
        atomicAdd(&acc[q1.z & (WIN_SIZE - 1)], __uint_as_float(q1.w));
    }
    // tail: the final partial quad (n % 4 entries)
    const unsigned i0 = n & ~3u;
    if ((unsigned)t < n - i0) {
        const uint2 e = buckets[base + i0 + t];
        atomicAdd(&acc[e.x & (WIN_SIZE - 1)], __uint_as_float(e.y));
    }
    __syncthreads();

    const int vb = b << WIN_SHIFT;
    #pragma unroll
    for (int i = 0; i < WIN_SIZE / 1024; ++i) {
        const int v = vb + t + i * 1024;
        if (v < n_points) out[v] += acc[t + i * 1024];  // += keeps overflow atomics
    }
}

// ---------------- Fallback: fused single pass (known-good, 588 us) ----------------
__global__ __launch_bounds__(256) void mesh_fused_kernel(
    const float* __restrict__ points,
    const int*   __restrict__ adj,
    const float* __restrict__ W1, const float* __restrict__ b1,
    const float* __restrict__ W2, const float* __restrict__ b2,
    const float* __restrict__ W3, const float* __restrict__ b3,
    const float* __restrict__ W4, const float* __restrict__ b4,
    float* __restrict__ out,
    int n_elems)
{
    const int e = blockIdx.x * 256 + threadIdx.x;
    if (e >= n_elems) return;
    const int i0 = adj[3 * e + 0], i1 = adj[3 * e + 1], i2 = adj[3 * e + 2];
    const float2* pts2 = (const float2*)points;
    const float2 p0 = pts2[i0], p1 = pts2[i1], p2 = pts2[i2];
    const float x[6] = { p0.x, p0.y, p1.x, p1.y, p2.x, p2.y };
    float o0, o1, o2;
    mlp3(x, W1, b1, W2, b2, W3, b3, W4, b4, o0, o1, o2);
    unsafeAtomicAdd(&out[i0], o0);
    unsafeAtomicAdd(&out[i1], o1);
    unsafeAtomicAdd(&out[i2], o2);
}

extern "C" void kernel_launch(void* const* d_in, const int* in_sizes, int n_in,
                              void* d_out, int out_size, void* d_ws, size_t ws_size,
                              hipStream_t stream) {
    const float* points = (const float*)d_in[0];
    const int*   adj    = (const int*)d_in[1];
    const float* W1 = (const float*)d_in[2];
    const float* b1 = (const float*)d_in[3];
    const float* W2 = (const float*)d_in[4];
    const float* b2 = (const float*)d_in[5];
    const float* W3 = (const float*)d_in[6];
    const float* b3 = (const float*)d_in[7];
    const float* W4 = (const float*)d_in[8];
    const float* b4 = (const float*)d_in[9];
    float* out = (float*)d_out;

    const int n_elems  = in_sizes[1] / 3;  // adjacency is [E,3]
    const int n_pairs  = in_sizes[1];
    const int n_points = out_size;
    const int block = 256;

    // ws layout: [gcount: 256 u32][buckets: K_BUCKETS * BUCKET_CAP uint2]
    const size_t need = 1024 + (size_t)K_BUCKETS * BUCKET_CAP * sizeof(uint2);

    if (ws_size >= need && n_points <= K_BUCKETS * WIN_SIZE) {
        unsigned* gcount = (unsigned*)d_ws;
        uint2* buckets = (uint2*)((char*)d_ws + 1024);

        hipMemsetAsync(gcount, 0, 1024, stream);
        hipMemsetAsync(out, 0, (size_t)n_points * sizeof(float), stream);

        const int gridA = (n_elems + CHUNK_E - 1) / CHUNK_E;
        mesh_bin_kernel<<<gridA, block, 0, stream>>>(
            points, adj, W1, b1, W2, b2, W3, b3, W4, b4,
            buckets, gcount, out, n_elems, n_pairs);

        mesh_reduce_kernel<<<K_BUCKETS, 1024, 0, stream>>>(
            buckets, gcount, out, n_points);
    } else {
        hipMemsetAsync(out, 0, (size_t)n_points * sizeof(float), stream);
        const int grid1 = (n_elems + block - 1) / block;
        mesh_fused_kernel<<<grid1, block, 0, stream>>>(
            points, adj, W1, b1, W2, b2, W3, b3, W4, b4, out, n_elems);
    }
}

// Round 8
// 420.488 us; speedup vs baseline: 1.9901x; 1.0850x over previous
//
#include <hip/hip_runtime.h>
#include <hip/hip_fp16.h>

// ---- binning geometry ----
#define WIN_SHIFT   13                 // vertex window = 8192 vertices
#define WIN_SIZE    (1 << WIN_SHIFT)
#define K_BUCKETS   245                // ceil(2,000,000 / 8192)
#define CAP_FULL    49664u             // mean 48980 + ~3.1 sigma (few overflows, netted)
#define CAP_MIN     47000u             // below this, per-bucket overflow gets expensive
#define CHUNK_E     2048               // elements per phase-A block
#define CHUNK_P     (3 * CHUNK_E)      // 6144 pairs per phase-A block

// sigmoid(x) = 1 / (1 + e^-x); __expf -> v_mul + v_exp_f32, rcpf -> v_rcp_f32.
__device__ __forceinline__ float sigmoidf_fast(float v) {
    return __builtin_amdgcn_rcpf(1.0f + __expf(-v));
}

// point readers: raw prefetch type, convert only at use (keeps load in flight)
__device__ __forceinline__ float2 to_f2(float2 p)  { return p; }
__device__ __forceinline__ float2 to_f2(__half2 p) { return __half22float2(p); }

// Tiny MLP 6->8->8->8->3, sigmoid after each layer. Weight loads are
// wave-uniform (kernel-arg pointers + compile-time indices) -> scalar s_load.
__device__ __forceinline__ void mlp3(
    const float x[6],
    const float* __restrict__ W1, const float* __restrict__ b1,
    const float* __restrict__ W2, const float* __restrict__ b2,
    const float* __restrict__ W3, const float* __restrict__ b3,
    const float* __restrict__ W4, const float* __restrict__ b4,
    float& o0, float& o1, float& o2)
{
    float h[8], g[8];
    #pragma unroll
    for (int j = 0; j < 8; ++j) h[j] = b1[j];
    #pragma unroll
    for (int i = 0; i < 6; ++i) {
        const float xi = x[i];
        #pragma unroll
        for (int j = 0; j < 8; ++j) h[j] = fmaf(xi, W1[i * 8 + j], h[j]);
    }
    #pragma unroll
    for (int j = 0; j < 8; ++j) h[j] = sigmoidf_fast(h[j]);
    #pragma unroll
    for (int j = 0; j < 8; ++j) g[j] = b2[j];
    #pragma unroll
    for (int i = 0; i < 8; ++i) {
        const float hi = h[i];
        #pragma unroll
        for (int j = 0; j < 8; ++j) g[j] = fmaf(hi, W2[i * 8 + j], g[j]);
    }
    #pragma unroll
    for (int j = 0; j < 8; ++j) g[j] = sigmoidf_fast(g[j]);
    #pragma unroll
    for (int j = 0; j < 8; ++j) h[j] = b3[j];
    #pragma unroll
    for (int i = 0; i < 8; ++i) {
        const float gi = g[i];
        #pragma unroll
        for (int j = 0; j < 8; ++j) h[j] = fmaf(gi, W3[i * 8 + j], h[j]);
    }
    #pragma unroll
    for (int j = 0; j < 8; ++j) h[j] = sigmoidf_fast(h[j]);
    float a0 = b4[0], a1 = b4[1], a2 = b4[2];
    #pragma unroll
    for (int i = 0; i < 8; ++i) {
        const float hi = h[i];
        a0 = fmaf(hi, W4[i * 3 + 0], a0);
        a1 = fmaf(hi, W4[i * 3 + 1], a1);
        a2 = fmaf(hi, W4[i * 3 + 2], a2);
    }
    o0 = sigmoidf_fast(a0);
    o1 = sigmoidf_fast(a1);
    o2 = sigmoidf_fast(a2);
}

__device__ __forceinline__ void scatter3(
    uint2* __restrict__ buckets, unsigned* cursor, const unsigned* gbase,
    float* __restrict__ out, unsigned cap,
    int v0, int v1, int v2, float w0, float w1, float w2)
{
    const int   vv[3] = { v0, v1, v2 };
    const float ww[3] = { w0, w1, w2 };
    #pragma unroll
    for (int k = 0; k < 3; ++k) {
        const unsigned v = (unsigned)vv[k];
        const unsigned b = v >> WIN_SHIFT;
        const unsigned loc  = atomicAdd(&cursor[b], 1u);   // ds_add_rtn
        const unsigned slot = gbase[b] + loc;
        if (slot < cap)
            buckets[(size_t)b * cap + slot] = make_uint2(v, __float_as_uint(ww[k]));
        else
            unsafeAtomicAdd(&out[v], ww[k]);               // rare; correctness net
    }
}

// -------- prologue: points fp32 -> half2 (halves gather L2 footprint) --------
__global__ __launch_bounds__(256) void conv_points_kernel(
    const float2* __restrict__ pts, __half2* __restrict__ ph, int n_points)
{
    const int i = blockIdx.x * 256 + threadIdx.x;
    if (i < n_points) {
        const float2 p = pts[i];
        ph[i] = __floats2half2_rn(p.x, p.y);
    }
}

// ---------------- Phase A: histogram -> reserve -> MLP + bin-scatter ----------------
template <typename PT>
__global__ __launch_bounds__(256) void mesh_bin_kernel(
    const PT*    __restrict__ pts,
    const int*   __restrict__ adj,
    const float* __restrict__ W1, const float* __restrict__ b1,
    const float* __restrict__ W2, const float* __restrict__ b2,
    const float* __restrict__ W3, const float* __restrict__ b3,
    const float* __restrict__ W4, const float* __restrict__ b4,
    uint2*    __restrict__ buckets,
    unsigned* __restrict__ gcount,    // [256] global bucket counters (pre-zeroed)
    float*    __restrict__ out,       // overflow fallback target (pre-zeroed)
    unsigned cap, int n_elems, int n_pairs)
{
    __shared__ unsigned hist[256];
    __shared__ unsigned gbase[256];
    __shared__ unsigned cursor[256];
    __shared__ int sadj[CHUNK_P];     // adj chunk cache: read global adj ONCE
    const int t = threadIdx.x;
    hist[t] = 0u;
    cursor[t] = 0u;
    __syncthreads();

    const bool full = (blockIdx.x + 1) * CHUNK_E <= n_elems;
    const int pbase = blockIdx.x * CHUNK_P;

    // 1) stage adj chunk into LDS + histogram (coalesced global reads, once)
    if (full) {
        #pragma unroll
        for (int i = 0; i < CHUNK_P / 256; ++i) {
            const int v = adj[pbase + t + i * 256];
            sadj[t + i * 256] = v;
            atomicAdd(&hist[((unsigned)v) >> WIN_SHIFT], 1u);
        }
    } else {
        for (int i = 0; i < CHUNK_P / 256; ++i) {
            const int j = pbase + t + i * 256;
            const int v = (j < n_pairs) ? adj[j] : 0;
            sadj[t + i * 256] = v;
            if (j < n_pairs) atomicAdd(&hist[((unsigned)v) >> WIN_SHIFT], 1u);
        }
    }
    __syncthreads();

    // 2) reserve contiguous global space per bucket
    {
        const unsigned c = hist[t];
        gbase[t] = c ? atomicAdd(&gcount[t], c) : 0u;
    }
    __syncthreads();

    // 3) software-pipelined gather + MLP + binned scatter:
    //    issue element i+1's 3 point loads (raw PT, no convert) before
    //    element i's MLP+scatter -> gather latency hidden behind compute.
    if (full) {
        int ida[3];
        PT  pa[3];
        {
            const int o = 3 * t;
            ida[0] = sadj[o]; ida[1] = sadj[o + 1]; ida[2] = sadj[o + 2];
            pa[0] = pts[ida[0]]; pa[1] = pts[ida[1]]; pa[2] = pts[ida[2]];
        }
        #pragma unroll
        for (int i = 0; i < CHUNK_E / 256; ++i) {
            int idb[3];
            PT  pb[3];
            if (i + 1 < CHUNK_E / 256) {
                const int o = 3 * (t + (i + 1) * 256);
                idb[0] = sadj[o]; idb[1] = sadj[o + 1]; idb[2] = sadj[o + 2];
                pb[0] = pts[idb[0]]; pb[1] = pts[idb[1]]; pb[2] = pts[idb[2]];
            }
            const float2 q0 = to_f2(pa[0]);
            const float2 q1 = to_f2(pa[1]);
            const float2 q2 = to_f2(pa[2]);
            const float x[6] = { q0.x, q0.y, q1.x, q1.y, q2.x, q2.y };
            float o0, o1, o2;
            mlp3(x, W1, b1, W2, b2, W3, b3, W4, b4, o0, o1, o2);
            scatter3(buckets, cursor, gbase, out, cap,
                     ida[0], ida[1], ida[2], o0, o1, o2);
            ida[0] = idb[0]; ida[1] = idb[1]; ida[2] = idb[2];
            pa[0] = pb[0]; pa[1] = pb[1]; pa[2] = pb[2];
        }
    } else {
        for (int i = 0; i < CHUNK_E / 256; ++i) {
            const int e = blockIdx.x * CHUNK_E + t + i * 256;
            if (e < n_elems) {
                const int o = 3 * (t + i * 256);
                const int i0 = sadj[o], i1 = sadj[o + 1], i2 = sadj[o + 2];
                const float2 q0 = to_f2(pts[i0]);
                const float2 q1 = to_f2(pts[i1]);
                const float2 q2 = to_f2(pts[i2]);
                const float x[6] = { q0.x, q0.y, q1.x, q1.y, q2.x, q2.y };
                float o0, o1, o2;
                mlp3(x, W1, b1, W2, b2, W3, b3, W4, b4, o0, o1, o2);
                scatter3(buckets, cursor, gbase, out, cap, i0, i1, i2, o0, o1, o2);
            }
        }
    }
}

// ---------------- Phase B: per-window LDS reduce -> coalesced out ----------------
__global__ __launch_bounds__(1024) void mesh_reduce_kernel(
    const uint2*    __restrict__ buckets,
    const unsigned* __restrict__ gcount,
    float* __restrict__ out, unsigned cap, int n_points)
{
    __shared__ float acc[WIN_SIZE];   // 32 KB
    const int t = threadIdx.x;
    const int b = blockIdx.x;
    #pragma unroll
    for (int i = 0; i < WIN_SIZE / 1024; ++i) acc[t + i * 1024] = 0.f;
    __syncthreads();

    const unsigned n = min(gcount[b], cap);
    const size_t base = (size_t)b * cap;

    for (unsigned i = t * 4u; i + 4u <= n; i += 1024u * 4u) {
        const uint4 q0 = *(const uint4*)(buckets + base + i);
        const uint4 q1 = *(const uint4*)(buckets + base + i + 2);
        atomicAdd(&acc[q0.x & (WIN_SIZE - 1)], __uint_as_float(q0.y));
        atomicAdd(&acc[q0.z & (WIN_SIZE - 1)], __uint_as_float(q0.w));
        atomicAdd(&acc[q1.x & (WIN_SIZE - 1)], __uint_as_float(q1.y));
        atomicAdd(&acc[q1.z & (WIN_SIZE - 1)], __uint_as_float(q1.w));
    }
    const unsigned i0 = n & ~3u;
    if ((unsigned)t < n - i0) {
        const uint2 e = buckets[base + i0 + t];
        atomicAdd(&acc[e.x & (WIN_SIZE - 1)], __uint_as_float(e.y));
    }
    __syncthreads();

    const int vb = b << WIN_SHIFT;
    #pragma unroll
    for (int i = 0; i < WIN_SIZE / 1024; ++i) {
        const int v = vb + t + i * 1024;
        if (v < n_points) out[v] += acc[t + i * 1024];  // += keeps overflow atomics
    }
}

// ---------------- Fallback: fused single pass (known-good, 588 us) ----------------
__global__ __launch_bounds__(256) void mesh_fused_kernel(
    const float* __restrict__ points,
    const int*   __restrict__ adj,
    const float* __restrict__ W1, const float* __restrict__ b1,
    const float* __restrict__ W2, const float* __restrict__ b2,
    const float* __restrict__ W3, const float* __restrict__ b3,
    const float* __restrict__ W4, const float* __restrict__ b4,
    float* __restrict__ out,
    int n_elems)
{
    const int e = blockIdx.x * 256 + threadIdx.x;
    if (e >= n_elems) return;
    const int i0 = adj[3 * e + 0], i1 = adj[3 * e + 1], i2 = adj[3 * e + 2];
    const float2* pts2 = (const float2*)points;
    const float2 p0 = pts2[i0], p1 = pts2[i1], p2 = pts2[i2];
    const float x[6] = { p0.x, p0.y, p1.x, p1.y, p2.x, p2.y };
    float o0, o1, o2;
    mlp3(x, W1, b1, W2, b2, W3, b3, W4, b4, o0, o1, o2);
    unsafeAtomicAdd(&out[i0], o0);
    unsafeAtomicAdd(&out[i1], o1);
    unsafeAtomicAdd(&out[i2], o2);
}

extern "C" void kernel_launch(void* const* d_in, const int* in_sizes, int n_in,
                              void* d_out, int out_size, void* d_ws, size_t ws_size,
                              hipStream_t stream) {
    const float* points = (const float*)d_in[0];
    const int*   adj    = (const int*)d_in[1];
    const float* W1 = (const float*)d_in[2];
    const float* b1 = (const float*)d_in[3];
    const float* W2 = (const float*)d_in[4];
    const float* b2 = (const float*)d_in[5];
    const float* W3 = (const float*)d_in[6];
    const float* b3 = (const float*)d_in[7];
    const float* W4 = (const float*)d_in[8];
    const float* b4 = (const float*)d_in[9];
    float* out = (float*)d_out;

    const int n_elems  = in_sizes[1] / 3;
    const int n_pairs  = in_sizes[1];
    const int n_points = out_size;
    const int block = 256;

    const size_t ph_bytes = (size_t)n_points * sizeof(__half2);  // 8 MB

    // choose a runtime bucket cap so [gcount | buckets | half-points] fits d_ws
    unsigned cap_half = 0;
    if (ws_size > 1024 + ph_bytes) {
        size_t c = (ws_size - 1024 - ph_bytes) / ((size_t)K_BUCKETS * sizeof(uint2));
        cap_half = (unsigned)min(c, (size_t)CAP_FULL) & ~1u;     // even for uint4 loads
    }
    unsigned cap_f32 = 0;
    if (ws_size > 1024) {
        size_t c = (ws_size - 1024) / ((size_t)K_BUCKETS * sizeof(uint2));
        cap_f32 = (unsigned)min(c, (size_t)CAP_FULL) & ~1u;
    }

    if (cap_half >= CAP_MIN && n_points <= K_BUCKETS * WIN_SIZE) {
        unsigned* gcount = (unsigned*)d_ws;
        uint2* buckets = (uint2*)((char*)d_ws + 1024);
        __half2* ph = (__half2*)((char*)d_ws + 1024 +
                                 (size_t)K_BUCKETS * cap_half * sizeof(uint2));

        hipMemsetAsync(gcount, 0, 1024, stream);
        hipMemsetAsync(out, 0, (size_t)n_points * sizeof(float), stream);

        conv_points_kernel<<<(n_points + 255) / 256, block, 0, stream>>>(
            (const float2*)points, ph, n_points);

        const int gridA = (n_elems + CHUNK_E - 1) / CHUNK_E;
        mesh_bin_kernel<__half2><<<gridA, block, 0, stream>>>(
            ph, adj, W1, b1, W2, b2, W3, b3, W4, b4,
            buckets, gcount, out, cap_half, n_elems, n_pairs);

        mesh_reduce_kernel<<<K_BUCKETS, 1024, 0, stream>>>(
            buckets, gcount, out, cap_half, n_points);
    } else if (cap_f32 >= CAP_MIN && n_points <= K_BUCKETS * WIN_SIZE) {
        unsigned* gcount = (unsigned*)d_ws;
        uint2* buckets = (uint2*)((char*)d_ws + 1024);

        hipMemsetAsync(gcount, 0, 1024, stream);
        hipMemsetAsync(out, 0, (size_t)n_points * sizeof(float), stream);

        const int gridA = (n_elems + CHUNK_E - 1) / CHUNK_E;
        mesh_bin_kernel<float2><<<gridA, block, 0, stream>>>(
            (const float2*)points, adj, W1, b1, W2, b2, W3, b3, W4, b4,
            buckets, gcount, out, cap_f32, n_elems, n_pairs);

        mesh_reduce_kernel<<<K_BUCKETS, 1024, 0, stream>>>(
            buckets, gcount, out, cap_f32, n_points);
    } else {
        hipMemsetAsync(out, 0, (size_t)n_points * sizeof(float), stream);
        const int grid1 = (n_elems + block - 1) / block;
        mesh_fused_kernel<<<grid1, block, 0, stream>>>(
            points, adj, W1, b1, W2, b2, W3, b3, W4, b4, out, n_elems);
    }
}

// Round 9
// 367.006 us; speedup vs baseline: 2.2802x; 1.1457x over previous
//
#include <hip/hip_runtime.h>
#include <hip/hip_fp16.h>

// ---- binning geometry ----
#define WIN_SHIFT   13                 // vertex window = 8192 vertices
#define WIN_SIZE    (1 << WIN_SHIFT)
#define K_BUCKETS   245                // ceil(2,000,000 / 8192)
#define CAP_FULL    49664u             // mean 48980 + ~3.1 sigma
#define CAP_MIN     47000u
#define CHUNK_E     1024               // elements per phase-A block (15.3 KB LDS -> 8 blocks/CU)
#define CHUNK_P     (3 * CHUNK_E)
#define FIXED_SCALE 16777216.0f        // 2^24 fixed-point for LDS u32 accumulate
#define FIXED_INV   (1.0f / 16777216.0f)

// sigmoid(x) = 1 / (1 + e^-x)
__device__ __forceinline__ float sigmoidf_fast(float v) {
    return __builtin_amdgcn_rcpf(1.0f + __expf(-v));
}

__device__ __forceinline__ float2 to_f2(float2 p)  { return p; }
__device__ __forceinline__ float2 to_f2(__half2 p) { return __half22float2(p); }

// Tiny MLP 6->8->8->8->3, sigmoid after each layer. Weight loads wave-uniform -> s_load.
__device__ __forceinline__ void mlp3(
    const float x[6],
    const float* __restrict__ W1, const float* __restrict__ b1,
    const float* __restrict__ W2, const float* __restrict__ b2,
    const float* __restrict__ W3, const float* __restrict__ b3,
    const float* __restrict__ W4, const float* __restrict__ b4,
    float& o0, float& o1, float& o2)
{
    float h[8], g[8];
    #pragma unroll
    for (int j = 0; j < 8; ++j) h[j] = b1[j];
    #pragma unroll
    for (int i = 0; i < 6; ++i) {
        const float xi = x[i];
        #pragma unroll
        for (int j = 0; j < 8; ++j) h[j] = fmaf(xi, W1[i * 8 + j], h[j]);
    }
    #pragma unroll
    for (int j = 0; j < 8; ++j) h[j] = sigmoidf_fast(h[j]);
    #pragma unroll
    for (int j = 0; j < 8; ++j) g[j] = b2[j];
    #pragma unroll
    for (int i = 0; i < 8; ++i) {
        const float hi = h[i];
        #pragma unroll
        for (int j = 0; j < 8; ++j) g[j] = fmaf(hi, W2[i * 8 + j], g[j]);
    }
    #pragma unroll
    for (int j = 0; j < 8; ++j) g[j] = sigmoidf_fast(g[j]);
    #pragma unroll
    for (int j = 0; j < 8; ++j) h[j] = b3[j];
    #pragma unroll
    for (int i = 0; i < 8; ++i) {
        const float gi = g[i];
        #pragma unroll
        for (int j = 0; j < 8; ++j) h[j] = fmaf(gi, W3[i * 8 + j], h[j]);
    }
    #pragma unroll
    for (int j = 0; j < 8; ++j) h[j] = sigmoidf_fast(h[j]);
    float a0 = b4[0], a1 = b4[1], a2 = b4[2];
    #pragma unroll
    for (int i = 0; i < 8; ++i) {
        const float hi = h[i];
        a0 = fmaf(hi, W4[i * 3 + 0], a0);
        a1 = fmaf(hi, W4[i * 3 + 1], a1);
        a2 = fmaf(hi, W4[i * 3 + 2], a2);
    }
    o0 = sigmoidf_fast(a0);
    o1 = sigmoidf_fast(a1);
    o2 = sigmoidf_fast(a2);
}

__device__ __forceinline__ void scatter3(
    uint2* __restrict__ buckets, unsigned* cursor, const unsigned* gbase,
    float* __restrict__ out, unsigned cap,
    int v0, int v1, int v2, float w0, float w1, float w2)
{
    const int   vv[3] = { v0, v1, v2 };
    const float ww[3] = { w0, w1, w2 };
    #pragma unroll
    for (int k = 0; k < 3; ++k) {
        const unsigned v = (unsigned)vv[k];
        const unsigned b = v >> WIN_SHIFT;
        const unsigned loc  = atomicAdd(&cursor[b], 1u);   // native ds_add_rtn_u32
        const unsigned slot = gbase[b] + loc;
        if (slot < cap)
            buckets[(size_t)b * cap + slot] = make_uint2(v, __float_as_uint(ww[k]));
        else
            unsafeAtomicAdd(&out[v], ww[k]);               // rare; correctness net
    }
}

// -------- prologue: points fp32 -> half2 --------
__global__ __launch_bounds__(256) void conv_points_kernel(
    const float2* __restrict__ pts, __half2* __restrict__ ph, int n_points)
{
    const int i = blockIdx.x * 256 + threadIdx.x;
    if (i < n_points) {
        const float2 p = pts[i];
        ph[i] = __floats2half2_rn(p.x, p.y);
    }
}

// ---------------- Phase A: histogram -> reserve -> MLP + bin-scatter ----------------
template <typename PT>
__global__ __launch_bounds__(256) void mesh_bin_kernel(
    const PT*    __restrict__ pts,
    const int*   __restrict__ adj,
    const float* __restrict__ W1, const float* __restrict__ b1,
    const float* __restrict__ W2, const float* __restrict__ b2,
    const float* __restrict__ W3, const float* __restrict__ b3,
    const float* __restrict__ W4, const float* __restrict__ b4,
    uint2*    __restrict__ buckets,
    unsigned* __restrict__ gcount,
    float*    __restrict__ out,
    unsigned cap, int n_elems, int n_pairs)
{
    __shared__ unsigned hist[256];
    __shared__ unsigned gbase[256];
    __shared__ unsigned cursor[256];
    __shared__ int sadj[CHUNK_P];     // 12 KB: adj chunk cached, global adj read ONCE
    const int t = threadIdx.x;
    hist[t] = 0u;
    cursor[t] = 0u;
    __syncthreads();

    const bool full = (blockIdx.x + 1) * CHUNK_E <= n_elems;
    const int pbase = blockIdx.x * CHUNK_P;

    if (full) {
        #pragma unroll
        for (int i = 0; i < CHUNK_P / 256; ++i) {
            const int v = adj[pbase + t + i * 256];
            sadj[t + i * 256] = v;
            atomicAdd(&hist[((unsigned)v) >> WIN_SHIFT], 1u);
        }
    } else {
        for (int i = 0; i < CHUNK_P / 256; ++i) {
            const int j = pbase + t + i * 256;
            const int v = (j < n_pairs) ? adj[j] : 0;
            sadj[t + i * 256] = v;
            if (j < n_pairs) atomicAdd(&hist[((unsigned)v) >> WIN_SHIFT], 1u);
        }
    }
    __syncthreads();

    {
        const unsigned c = hist[t];
        gbase[t] = c ? atomicAdd(&gcount[t], c) : 0u;
    }
    __syncthreads();

    // software-pipelined gather + MLP + binned scatter (prefetch depth 1)
    if (full) {
        int ida[3];
        PT  pa[3];
        {
            const int o = 3 * t;
            ida[0] = sadj[o]; ida[1] = sadj[o + 1]; ida[2] = sadj[o + 2];
            pa[0] = pts[ida[0]]; pa[1] = pts[ida[1]]; pa[2] = pts[ida[2]];
        }
        #pragma unroll
        for (int i = 0; i < CHUNK_E / 256; ++i) {
            int idb[3] = {0, 0, 0};
            PT  pb[3];
            if (i + 1 < CHUNK_E / 256) {
                const int o = 3 * (t + (i + 1) * 256);
                idb[0] = sadj[o]; idb[1] = sadj[o + 1]; idb[2] = sadj[o + 2];
                pb[0] = pts[idb[0]]; pb[1] = pts[idb[1]]; pb[2] = pts[idb[2]];
            }
            const float2 q0 = to_f2(pa[0]);
            const float2 q1 = to_f2(pa[1]);
            const float2 q2 = to_f2(pa[2]);
            const float x[6] = { q0.x, q0.y, q1.x, q1.y, q2.x, q2.y };
            float o0, o1, o2;
            mlp3(x, W1, b1, W2, b2, W3, b3, W4, b4, o0, o1, o2);
            scatter3(buckets, cursor, gbase, out, cap,
                     ida[0], ida[1], ida[2], o0, o1, o2);
            ida[0] = idb[0]; ida[1] = idb[1]; ida[2] = idb[2];
            pa[0] = pb[0]; pa[1] = pb[1]; pa[2] = pb[2];
        }
    } else {
        for (int i = 0; i < CHUNK_E / 256; ++i) {
            const int e = blockIdx.x * CHUNK_E + t + i * 256;
            if (e < n_elems) {
                const int o = 3 * (t + i * 256);
                const int i0 = sadj[o], i1 = sadj[o + 1], i2 = sadj[o + 2];
                const float2 q0 = to_f2(pts[i0]);
                const float2 q1 = to_f2(pts[i1]);
                const float2 q2 = to_f2(pts[i2]);
                const float x[6] = { q0.x, q0.y, q1.x, q1.y, q2.x, q2.y };
                float o0, o1, o2;
                mlp3(x, W1, b1, W2, b2, W3, b3, W4, b4, o0, o1, o2);
                scatter3(buckets, cursor, gbase, out, cap, i0, i1, i2, o0, o1, o2);
            }
        }
    }
}

// ---------------- Phase B: per-window LDS reduce (u32 fixed-point) ----------------
// Round 6->7 showed this phase invariant (~160us) under 16x parallelism -> suspected
// fp32 LDS atomicAdd lowers to a CAS loop. u32 atomicAdd is guaranteed native
// ds_add_u32. Weights in (0,1) * 2^24; degree <= ~40 -> sum < 2^30, no overflow.
__global__ __launch_bounds__(1024) void mesh_reduce_kernel(
    const uint2*    __restrict__ buckets,
    const unsigned* __restrict__ gcount,
    float* __restrict__ out, unsigned cap, int n_points)
{
    __shared__ unsigned acc[WIN_SIZE];   // 32 KB
    const int t = threadIdx.x;
    const int b = blockIdx.x;
    #pragma unroll
    for (int i = 0; i < WIN_SIZE / 1024; ++i) acc[t + i * 1024] = 0u;
    __syncthreads();

    const unsigned n = min(gcount[b], cap);
    const size_t base = (size_t)b * cap;

    for (unsigned i = t * 4u; i + 4u <= n; i += 1024u * 4u) {
        const uint4 q0 = *(const uint4*)(buckets + base + i);
        const uint4 q1 = *(const uint4*)(buckets + base + i + 2);
        atomicAdd(&acc[q0.x & (WIN_SIZE - 1)],
                  (unsigned)__float2uint_rn(__uint_as_float(q0.y) * FIXED_SCALE));
        atomicAdd(&acc[q0.z & (WIN_SIZE - 1)],
                  (unsigned)__float2uint_rn(__uint_as_float(q0.w) * FIXED_SCALE));
        atomicAdd(&acc[q1.x & (WIN_SIZE - 1)],
                  (unsigned)__float2uint_rn(__uint_as_float(q1.y) * FIXED_SCALE));
        atomicAdd(&acc[q1.z & (WIN_SIZE - 1)],
                  (unsigned)__float2uint_rn(__uint_as_float(q1.w) * FIXED_SCALE));
    }
    const unsigned i0 = n & ~3u;
    if ((unsigned)t < n - i0) {
        const uint2 e = buckets[base + i0 + t];
        atomicAdd(&acc[e.x & (WIN_SIZE - 1)],
                  (unsigned)__float2uint_rn(__uint_as_float(e.y) * FIXED_SCALE));
    }
    __syncthreads();

    const int vb = b << WIN_SHIFT;
    #pragma unroll
    for (int i = 0; i < WIN_SIZE / 1024; ++i) {
        const int v = vb + t + i * 1024;
        if (v < n_points)
            out[v] += (float)acc[t + i * 1024] * FIXED_INV;  // += keeps overflow atomics
    }
}

// ---------------- Fallback: fused single pass (known-good, 588 us) ----------------
__global__ __launch_bounds__(256) void mesh_fused_kernel(
    const float* __restrict__ points,
    const int*   __restrict__ adj,
    const float* __restrict__ W1, const float* __restrict__ b1,
    const float* __restrict__ W2, const float* __restrict__ b2,
    const float* __restrict__ W3, const float* __restrict__ b3,
    const float* __restrict__ W4, const float* __restrict__ b4,
    float* __restrict__ out,
    int n_elems)
{
    const int e = blockIdx.x * 256 + threadIdx.x;
    if (e >= n_elems) return;
    const int i0 = adj[3 * e + 0], i1 = adj[3 * e + 1], i2 = adj[3 * e + 2];
    const float2* pts2 = (const float2*)points;
    const float2 p0 = pts2[i0], p1 = pts2[i1], p2 = pts2[i2];
    const float x[6] = { p0.x, p0.y, p1.x, p1.y, p2.x, p2.y };
    float o0, o1, o2;
    mlp3(x, W1, b1, W2, b2, W3, b3, W4, b4, o0, o1, o2);
    unsafeAtomicAdd(&out[i0], o0);
    unsafeAtomicAdd(&out[i1], o1);
    unsafeAtomicAdd(&out[i2], o2);
}

extern "C" void kernel_launch(void* const* d_in, const int* in_sizes, int n_in,
                              void* d_out, int out_size, void* d_ws, size_t ws_size,
                              hipStream_t stream) {
    const float* points = (const float*)d_in[0];
    const int*   adj    = (const int*)d_in[1];
    const float* W1 = (const float*)d_in[2];
    const float* b1 = (const float*)d_in[3];
    const float* W2 = (const float*)d_in[4];
    const float* b2 = (const float*)d_in[5];
    const float* W3 = (const float*)d_in[6];
    const float* b3 = (const float*)d_in[7];
    const float* W4 = (const float*)d_in[8];
    const float* b4 = (const float*)d_in[9];
    float* out = (float*)d_out;

    const int n_elems  = in_sizes[1] / 3;
    const int n_pairs  = in_sizes[1];
    const int n_points = out_size;
    const int block = 256;

    const size_t ph_bytes = (size_t)n_points * sizeof(__half2);

    unsigned cap_half = 0;
    if (ws_size > 1024 + ph_bytes) {
        size_t c = (ws_size - 1024 - ph_bytes) / ((size_t)K_BUCKETS * sizeof(uint2));
        cap_half = (unsigned)min(c, (size_t)CAP_FULL) & ~1u;
    }
    unsigned cap_f32 = 0;
    if (ws_size > 1024) {
        size_t c = (ws_size - 1024) / ((size_t)K_BUCKETS * sizeof(uint2));
        cap_f32 = (unsigned)min(c, (size_t)CAP_FULL) & ~1u;
    }

    if (cap_half >= CAP_MIN && n_points <= K_BUCKETS * WIN_SIZE) {
        unsigned* gcount = (unsigned*)d_ws;
        uint2* buckets = (uint2*)((char*)d_ws + 1024);
        __half2* ph = (__half2*)((char*)d_ws + 1024 +
                                 (size_t)K_BUCKETS * cap_half * sizeof(uint2));

        hipMemsetAsync(gcount, 0, 1024, stream);
        hipMemsetAsync(out, 0, (size_t)n_points * sizeof(float), stream);

        conv_points_kernel<<<(n_points + 255) / 256, block, 0, stream>>>(
            (const float2*)points, ph, n_points);

        const int gridA = (n_elems + CHUNK_E - 1) / CHUNK_E;
        mesh_bin_kernel<__half2><<<gridA, block, 0, stream>>>(
            ph, adj, W1, b1, W2, b2, W3, b3, W4, b4,
            buckets, gcount, out, cap_half, n_elems, n_pairs);

        mesh_reduce_kernel<<<K_BUCKETS, 1024, 0, stream>>>(
            buckets, gcount, out, cap_half, n_points);
    } else if (cap_f32 >= CAP_MIN && n_points <= K_BUCKETS * WIN_SIZE) {
        unsigned* gcount = (unsigned*)d_ws;
        uint2* buckets = (uint2*)((char*)d_ws + 1024);

        hipMemsetAsync(gcount, 0, 1024, stream);
        hipMemsetAsync(out, 0, (size_t)n_points * sizeof(float), stream);

        const int gridA = (n_elems + CHUNK_E - 1) / CHUNK_E;
        mesh_bin_kernel<float2><<<gridA, block, 0, stream>>>(
            (const float2*)points, adj, W1, b1, W2, b2, W3, b3, W4, b4,
            buckets, gcount, out, cap_f32, n_elems, n_pairs);

        mesh_reduce_kernel<<<K_BUCKETS, 1024, 0, stream>>>(
            buckets, gcount, out, cap_f32, n_points);
    } else {
        hipMemsetAsync(out, 0, (size_t)n_points * sizeof(float), stream);
        const int grid1 = (n_elems + block - 1) / block;
        mesh_fused_kernel<<<grid1, block, 0, stream>>>(
            points, adj, W1, b1, W2, b2, W3, b3, W4, b4, out, n_elems);
    }
}